// Round 10
// baseline (1462.572 us; speedup 1.0000x reference)
//
#include <hip/hip_runtime.h>
#include <hip/hip_bf16.h>
#include <cstdint>
#include <cstddef>

#define B_    64
#define N_    2048
#define E_    32768            // edges per graph
#define DIM_  64
#define K1_   1639
#define K2_   1312
#define NTOT  (B_ * N_)        // 131072
#define ETOT  (B_ * E_)        // 2097152
#define N2TOT (B_ * K1_)       // 104896
#define NCLS  6
#define PB_   8                // pool blocks per graph (index-partitioned)
#define CHUNKS_ 16             // dst-chunks per graph (128-node chunks; stage2 uses 13)
#define SLICES_ 16             // edge slices per graph in k_bucket
#define BCAP  3072             // bucket capacity (= SLICES_*REG_)
#define REG_  192              // per-slice region headroom

typedef float f4 __attribute__((ext_vector_type(4)));
typedef _Float16 h2 __attribute__((ext_vector_type(2)));
typedef _Float16 h8 __attribute__((ext_vector_type(8)));

static __device__ __forceinline__ h2 pkrtz(float a, float b) {
    return __builtin_bit_cast(h2, __builtin_amdgcn_cvt_pkrtz(a, b));
}
static __device__ __forceinline__ unsigned long long mk_key(float s, int i) {
    unsigned u = __float_as_uint(s);
    u = (u & 0x80000000u) ? ~u : (u | 0x80000000u);
    return ((unsigned long long)u << 11) | (unsigned long long)(2047 - i);
}

// ---------------- one-time W fragment prep: f16 hi/lo MFMA B-fragments --------------------
// layout: wf[stage][ks][nt][hl][lane] as h8 (16B); 1024 h8 per stage (16KB)
__launch_bounds__(128)
__global__ void k_wprep(const float* W1, const float* W2, h8* wf) {
    int t = threadIdx.x;
    int stage = t >> 6, lane = t & 63;
    const float* W = stage ? W2 : W1;
    int q = lane >> 4, c = lane & 15;
#pragma unroll
    for (int ks = 0; ks < 2; ks++)
#pragma unroll
        for (int nt = 0; nt < 4; nt++) {
            h8 h, l;
#pragma unroll
            for (int j = 0; j < 8; j++) {
                float wv = W[(ks * 32 + q * 8 + j) * 64 + nt * 16 + c];
                _Float16 hh = (_Float16)wv;
                h[j] = hh;
                l[j] = (_Float16)(wv - (float)hh);
            }
            wf[(size_t)stage * 1024 + (((ks * 4 + nt) * 2 + 0) * 64) + lane] = h;
            wf[(size_t)stage * 1024 + (((ks * 4 + nt) * 2 + 1) * 64) + lane] = l;
        }
}

// ---------------- bucket edges by (graph, 128-node dst-chunk) + per-node degree ------------
template<int STAGE>
__launch_bounds__(256)
__global__ void k_bucket(const int* src, const int* dst, const int* remap,
                         int* bcnt, unsigned int* blist, int* deg) {
    const int NL = (STAGE == 1) ? N_ : K1_;
    __shared__ unsigned int lb[CHUNKS_][REG_];
    __shared__ int lc[CHUNKS_];
    __shared__ int rm[N_];                     // stage2 only
    __shared__ int sdeg[N_];
    int b = blockIdx.x;
    int g = b & 63, slice = b >> 6;
    int tid = threadIdx.x;
    if (tid < CHUNKS_) lc[tid] = 0;
    for (int i = tid; i < NL; i += 256) sdeg[i] = 0;
    if (STAGE == 2)
        for (int i = tid; i < N_; i += 256) rm[i] = remap[g * N_ + i];
    __syncthreads();
    const int ESL = E_ / SLICES_;              // 2048
    const int* sp = src + (size_t)g * E_ + slice * ESL;
    const int* dp = dst + (size_t)g * E_ + slice * ESL;
    int gbase = g * NL;
    for (int e = tid * 4; e < ESL; e += 1024) {
        int4 ss = *(const int4*)&sp[e];
        int4 dd = *(const int4*)&dp[e];
#pragma unroll
        for (int t = 0; t < 4; t++) {
            int s = (&ss.x)[t], d = (&dd.x)[t];
            if (STAGE == 2) {
                s = rm[s & (N_ - 1)]; d = rm[d & (N_ - 1)];
                if ((s | d) < 0) continue;     // edge touches a dropped node
                s -= gbase; d -= gbase;
            } else {
                s &= (N_ - 1); d &= (N_ - 1);
            }
            atomicAdd(&sdeg[d], 1);
            int ch = d >> 7;                   // 128-node chunks (both stages)
            int dl = d & 127;
            int p = atomicAdd(&lc[ch], 1);
            if (p < REG_) lb[ch][p] = ((unsigned)dl << 12) | (unsigned)s;
        }
    }
    __syncthreads();
    for (int ch = 0; ch < CHUNKS_; ch++) {
        int n = min(lc[ch], REG_);
        unsigned int* out = blist + (size_t)(g * CHUNKS_ + ch) * BCAP + slice * REG_;
        for (int i = tid; i < n; i += 256) out[i] = lb[ch][i];
    }
    if (tid < CHUNKS_) bcnt[(g * SLICES_ + slice) * CHUNKS_ + tid] = min(lc[tid], REG_);
    for (int i = tid; i < NL; i += 256) {
        int v = sdeg[i];
        if (v) atomicAdd(&deg[gbase + i], v);
    }
}

// ---------------- prescale: xb[node] = f16(x[node] * rsqrt(deg+1)) -------------------------
template<int STAGE>
__launch_bounds__(256)
__global__ void k_prescale(const float* xf, const unsigned int* xg, const int* deg,
                           unsigned int* xb) {
    const int TOT = ((STAGE == 1) ? NTOT : N2TOT) * 32;
    int stride = gridDim.x * 256;
    for (int idx = blockIdx.x * 256 + threadIdx.x; idx < TOT; idx += stride) {
        int node = idx >> 5;
        float sc = rsqrtf((float)(deg[node] + 1));
        float2 v;
        if (STAGE == 1) {
            v = ((const float2*)xf)[idx];
        } else {
            h2 hv = __builtin_bit_cast(h2, xg[idx]);
            v.x = (float)hv.x; v.y = (float)hv.y;
        }
        h2 o = {(_Float16)(v.x * sc), (_Float16)(v.y * sc)};
        xb[idx] = __builtin_bit_cast(unsigned int, o);
    }
}

// ---------------- FUSED scatter-aggregate (LDS f32 atomics) + MFMA conv --------------------
// Block = (graph, 128-node chunk). Init: LDS tile seeded with self rows (f16->f32,
// 16B-chunk XOR swizzle chunk^=(row&7)). Scatter: each half-wave streams bucket edges;
// per edge one coalesced 128B row load + 2 ds_add_f32 per lane -- every edge independent,
// NO dependency chain, no sort/CSR needed (r5-r9 evidence: the gather chain only ever
// responded to wave count, not scheduling). Conv: same MFMA f16 hi/lo on the tile, with
// the dst-side rsqrt(deg+1) folded into the A-fragment build.
template<int STAGE>
__launch_bounds__(256, 4)
__global__ void k_scatconv(const unsigned int* xb, const int* deg, const int* bcnt,
                           const unsigned int* blist, const h8* wfrag,
                           const float* bias, const float* pvec,
                           float* y, float* score) {
    const int NL  = (STAGE == 1) ? N_ : K1_;
    const int NCH = (STAGE == 1) ? 16 : 13;
    __shared__ float ls[128 * 64];             // 32KB swizzled f32 accum tile
    __shared__ float rds[128];
    __shared__ int cnt_s[SLICES_];
    int b = blockIdx.x;
    int xcd = b & 7, idx = b >> 3;             // XCD keeps 8 consecutive graphs
    int g = xcd * 8 + idx / NCH;
    int ch = idx % NCH;
    int tid = threadIdx.x;
    int lim = min(128, NL - ch * 128);
    int gbase = g * NL;
    if (tid < SLICES_) cnt_s[tid] = bcnt[(g * SLICES_ + tid) * CHUNKS_ + ch];
    for (int i = tid; i < 128; i += 256)
        rds[i] = (i < lim) ? rsqrtf((float)(deg[gbase + ch * 128 + i] + 1)) : 0.f;
    for (int i = tid; i < 128 * 32; i += 256) {
        int r = i >> 5, l = i & 31;
        float2 v = {0.f, 0.f};
        if (r < lim) {
            h2 hv = __builtin_bit_cast(h2, xb[(size_t)(gbase + ch * 128 + r) * 32 + l]);
            v.x = (float)hv.x; v.y = (float)hv.y;
        }
        int phys = r * 64 + (((l >> 1) ^ (r & 7)) << 2) + (l & 1) * 2;
        *(float2*)&ls[phys] = v;
    }
    __syncthreads();
    // ---- scatter phase: half-wave per edge ----
    int hw = tid >> 5, l32 = tid & 31;
    int lc1 = l32 >> 1, lc2 = (l32 & 1) * 2;
    const unsigned int* xg32 = xb + (size_t)gbase * 32;
    for (int sl = 0; sl < SLICES_; sl++) {
        int n = cnt_s[sl];
        const unsigned int* bl = blist + (size_t)(g * CHUNKS_ + ch) * BCAP + sl * REG_;
        for (int i = hw; i < n; i += 8) {
            unsigned pk = bl[i];
            int dl = (int)(pk >> 12), s = (int)(pk & 0xFFFu);
            h2 hv = __builtin_bit_cast(h2, xg32[s * 32 + l32]);
            int phys = dl * 64 + ((lc1 ^ (dl & 7)) << 2) + lc2;
            atomicAdd(&ls[phys],     (float)hv.x);
            atomicAdd(&ls[phys + 1], (float)hv.y);
        }
    }
    __syncthreads();
    // ---- conv phase: 128 rows = 2 sub-tiles x 4 waves x 16 rows ----
    const h8* wsrc = wfrag + ((STAGE == 2) ? 1024 : 0);
    const float4* ls4 = (const float4*)ls;
    int wid = tid >> 6, lane = tid & 63;
    int q = lane >> 4, c = lane & 15;
    float pp = 0.f;
#pragma unroll
    for (int i = 0; i < DIM_; i++) pp += pvec[i] * pvec[i];
    float rpn = rsqrtf(pp);
#pragma unroll 1
    for (int s = 0; s < 2; s++) {
        int rl = s * 64 + wid * 16;            // local row base of this wave's 16 rows
        int row = rl + c;
        int rl16 = row * 16;
        int cx = row & 7;
        float rd = rds[row];
        h8 ah[2], al[2];
#pragma unroll
        for (int ks = 0; ks < 2; ks++) {
            float4 v0 = ls4[rl16 + ((ks * 8 + q * 2 + 0) ^ cx)];
            float4 v1 = ls4[rl16 + ((ks * 8 + q * 2 + 1) ^ cx)];
            float vv[8] = {v0.x * rd, v0.y * rd, v0.z * rd, v0.w * rd,
                           v1.x * rd, v1.y * rd, v1.z * rd, v1.w * rd};
            h8 h, l;
#pragma unroll
            for (int j = 0; j < 8; j += 2) {
                h2 hp = pkrtz(vv[j], vv[j + 1]);
                float r0 = vv[j]     - (float)hp.x;
                float r1 = vv[j + 1] - (float)hp.y;
                h2 lp = pkrtz(r0, r1);
                h[j] = hp.x; h[j + 1] = hp.y;
                l[j] = lp.x; l[j + 1] = lp.y;
            }
            ah[ks] = h; al[ks] = l;
        }
        float dot[4] = {0.f, 0.f, 0.f, 0.f};
#pragma unroll
        for (int nt = 0; nt < 4; nt++) {
            f4 acc = {0.f, 0.f, 0.f, 0.f};
#pragma unroll
            for (int ks = 0; ks < 2; ks++) {
                h8 wh = wsrc[(((ks * 4 + nt) * 2 + 0) * 64) + lane];
                h8 wl = wsrc[(((ks * 4 + nt) * 2 + 1) * 64) + lane];
                acc = __builtin_amdgcn_mfma_f32_16x16x32_f16(ah[ks], wh, acc, 0, 0, 0);
                acc = __builtin_amdgcn_mfma_f32_16x16x32_f16(ah[ks], wl, acc, 0, 0, 0);
                acc = __builtin_amdgcn_mfma_f32_16x16x32_f16(al[ks], wh, acc, 0, 0, 0);
            }
            float bcol = bias[nt * 16 + c];
            float pcol = pvec[nt * 16 + c];
#pragma unroll
            for (int reg = 0; reg < 4; reg++) {
                float v = fmaxf(acc[reg] + bcol, 0.f);
                dot[reg] += v * pcol;
                int grow = rl + q * 4 + reg;
                if (grow < lim)
                    y[(size_t)(gbase + ch * 128 + grow) * DIM_ + nt * 16 + c] = v;
            }
        }
#pragma unroll
        for (int m = 1; m < 16; m <<= 1) {
#pragma unroll
            for (int reg = 0; reg < 4; reg++) dot[reg] += __shfl_xor(dot[reg], m);
        }
        if (c == 0) {
#pragma unroll
            for (int reg = 0; reg < 4; reg++) {
                int grow = rl + q * 4 + reg;
                if (grow < lim)
                    score[gbase + ch * 128 + grow] = tanhf(dot[reg] * rpn);
            }
        }
    }
}

// ---------------- exact K-th-largest key per graph (6-pass radix) --------------
template<int STAGE>
__launch_bounds__(256)
__global__ void k_thresh(const float* score, unsigned long long* thresh) {
    const int Nin = (STAGE == 1) ? N_ : K1_;
    const int K   = (STAGE == 1) ? K1_ : K2_;
    __shared__ unsigned long long keys[N_];
    __shared__ int bins[256], wsum[4];
    __shared__ unsigned long long s_prefix;
    __shared__ int s_need;
    int g = blockIdx.x, tid = threadIdx.x;
    int l64 = tid & 63, wid = tid >> 6;
    const float* sg = score + (size_t)g * Nin;
    for (int i = tid; i < Nin; i += 256) keys[i] = mk_key(sg[i], i);
    if (tid == 0) { s_need = K; s_prefix = 0ull; }
    __syncthreads();
    for (int shift = 40; shift >= 0; shift -= 8) {
        bins[tid] = 0;
        __syncthreads();
        unsigned long long pref = s_prefix;
        int need = s_need;
        int hi = shift + 8;
        for (int i = tid; i < Nin; i += 256) {
            unsigned long long k = keys[i];
            if ((k >> hi) == pref) atomicAdd(&bins[(int)((k >> shift) & 255)], 1);
        }
        __syncthreads();
        int mine = bins[tid];
        int v = mine;
#pragma unroll
        for (int o = 1; o < 64; o <<= 1) {     // wave suffix scan
            int t = __shfl_down(v, o);
            if (l64 + o < 64) v += t;
        }
        if (l64 == 0) wsum[wid] = v;
        __syncthreads();
        for (int w = wid + 1; w < 4; w++) v += wsum[w];
        int nxt = v - mine;
        if (v >= need && nxt < need) {         // exactly one tid matches
            s_prefix = (pref << 8) | (unsigned long long)tid;
            s_need = need - nxt;
        }
        __syncthreads();
    }
    if (tid == 0) thresh[g] = s_prefix;
}

// ---------------- pool (+rank/newid/xg in stage1), PB_ blocks/graph, threshold handoff ------
template<int STAGE>
__launch_bounds__(256)
__global__ void k_pool(const float* score, const float* conv, const unsigned long long* thresh,
                       int* new_id, unsigned int* xg, float* part) {
    const int Nin = (STAGE == 1) ? N_ : K1_;
    const int RNG = (STAGE == 1) ? (N_ / PB_) : ((K1_ + PB_ - 1) / PB_);  // 256 / 205
    __shared__ int rnk[256];
    __shared__ unsigned char keepf[256];
    __shared__ int wsum[4], s_base[4];
    __shared__ float rmx[4][64], rsm[4][64];
    int b = blockIdx.x;
    int g = b & 63, pb = b >> 6;
    int tid = threadIdx.x;
    int l64 = tid & 63, wid = tid >> 6;
    const float* sg = score + (size_t)g * Nin;
    unsigned long long T = thresh[g];
    int R0 = pb * RNG;
    int R1 = min(R0 + RNG, Nin);
    if (STAGE == 1) {
        int cb = 0;
        for (int i = tid; i < R0; i += 256) cb += (mk_key(sg[i], i) >= T) ? 1 : 0;
#pragma unroll
        for (int o = 32; o; o >>= 1) cb += __shfl_down(cb, o);
        if (l64 == 0) s_base[wid] = cb;
        int i = R0 + tid;
        int keep = (i < R1 && mk_key(sg[i], i) >= T) ? 1 : 0;
        keepf[tid] = (unsigned char)keep;
        int v = keep;
#pragma unroll
        for (int o = 1; o < 64; o <<= 1) {
            int t = __shfl_up(v, o);
            if (l64 >= o) v += t;
        }
        if (l64 == 63) wsum[wid] = v;
        __syncthreads();
        int base = s_base[0] + s_base[1] + s_base[2] + s_base[3];
        int wbase = 0;
        for (int w = 0; w < wid; w++) wbase += wsum[w];
        int r = base + wbase + v - keep;
        rnk[tid] = r;
        if (i < Nin) new_id[g * N_ + i] = keep ? (g * K1_ + r) : -1;
    } else {
        int i = R0 + tid;
        keepf[tid] = (unsigned char)((i < R1 && mk_key(sg[i], i) >= T) ? 1 : 0);
    }
    __syncthreads();
    float mx = -3.402823466e38f, sm = 0.f;
    for (int i = R0 + wid; i < R1; i += 4) {
        if (!keepf[i - R0]) continue;
        float val = sg[i];
        float v = conv[(size_t)(g * Nin + i) * DIM_ + l64] * val;
        mx = fmaxf(mx, v);
        sm += v;
        if (STAGE == 1) {
            float vo = __shfl_xor(v, 1);
            if (!(l64 & 1)) {
                h2 pk2 = {(_Float16)v, (_Float16)vo};
                xg[(size_t)(g * K1_ + rnk[i - R0]) * 32 + (l64 >> 1)] =
                    __builtin_bit_cast(unsigned int, pk2);
            }
        }
    }
    rmx[wid][l64] = mx; rsm[wid][l64] = sm;
    __syncthreads();
    if (wid == 0) {
        mx = fmaxf(fmaxf(rmx[0][l64], rmx[1][l64]), fmaxf(rmx[2][l64], rmx[3][l64]));
        sm = rsm[0][l64] + rsm[1][l64] + rsm[2][l64] + rsm[3][l64];
        part[((size_t)(g * PB_ + pb) * 2 + 0) * 64 + l64] = mx;
        part[((size_t)(g * PB_ + pb) * 2 + 1) * 64 + l64] = sm;
    }
}

// ---------------- MLP head (combines both stages' partials) ----------------
__launch_bounds__(64)
__global__ void k_head(const float* part1, const float* part2,
                       const float* l1w, const float* l1b,
                       const float* l2w, const float* l2b, float* out) {
    __shared__ float h[128];
    __shared__ float h1[64];
    int g = blockIdx.x, t = threadIdx.x;
    float mx1 = -3.402823466e38f, sm1 = 0.f, mx2 = -3.402823466e38f, sm2 = 0.f;
#pragma unroll
    for (int c = 0; c < PB_; c++) {
        mx1 = fmaxf(mx1, part1[((size_t)(g * PB_ + c) * 2 + 0) * 64 + t]);
        sm1 += part1[((size_t)(g * PB_ + c) * 2 + 1) * 64 + t];
        mx2 = fmaxf(mx2, part2[((size_t)(g * PB_ + c) * 2 + 0) * 64 + t]);
        sm2 += part2[((size_t)(g * PB_ + c) * 2 + 1) * 64 + t];
    }
    h[t]      = mx1 + mx2;
    h[t + 64] = sm1 / (float)K1_ + sm2 / (float)K2_;
    __syncthreads();
    float acc = l1b[t];
#pragma unroll 8
    for (int i = 0; i < 128; i++) acc += h[i] * l1w[i * 64 + t];
    h1[t] = fmaxf(acc, 0.0f);
    __syncthreads();
    if (t < NCLS) {
        float o = l2b[t];
#pragma unroll
        for (int i = 0; i < 64; i++) o += h1[i] * l2w[i * NCLS + t];
        out[g * NCLS + t] = o;
    }
}

extern "C" void kernel_launch(void* const* d_in, const int* in_sizes, int n_in,
                              void* d_out, int out_size, void* d_ws, size_t ws_size,
                              hipStream_t stream) {
    const float* x   = (const float*)d_in[0];
    const int*   ei  = (const int*)d_in[1];
    const int*   src = ei;
    const int*   dst = ei + ETOT;
    const float* W1  = (const float*)d_in[3];
    const float* b1  = (const float*)d_in[4];
    const float* p1  = (const float*)d_in[5];
    const float* W2  = (const float*)d_in[6];
    const float* b2  = (const float*)d_in[7];
    const float* p2  = (const float*)d_in[8];
    const float* l1w = (const float*)d_in[9];
    const float* l1b = (const float*)d_in[10];
    const float* l2w = (const float*)d_in[11];
    const float* l2b = (const float*)d_in[12];
    (void)in_sizes; (void)n_in; (void)out_size; (void)ws_size;

    // workspace layout; xg aliases bufB (dead until scatconv2 writes it)
    char* ws = (char*)d_ws;
    size_t off = 0;
    auto alloc = [&](size_t bytes) -> void* {
        void* p = ws + off;
        off = (off + bytes + 255) & ~(size_t)255;
        return p;
    };
    float*              bufA   = (float*)             alloc((size_t)NTOT  * DIM_ * 4);
    float*              bufB   = (float*)             alloc((size_t)N2TOT * DIM_ * 4);
    unsigned int*       blist  = (unsigned int*)      alloc((size_t)B_ * CHUNKS_ * BCAP * 4);
    unsigned int*       xb     = (unsigned int*)      alloc((size_t)NTOT * 32 * 4);
    int*                bcnt   = (int*)               alloc((size_t)B_ * SLICES_ * CHUNKS_ * 4);
    int*                deg    = (int*)               alloc((size_t)NTOT * 4);
    float*              score  = (float*)             alloc((size_t)NTOT * 4);
    int*                newid  = (int*)               alloc((size_t)NTOT * 4);
    unsigned long long* thr    = (unsigned long long*)alloc((size_t)B_ * 8);
    float*              part1  = (float*)             alloc((size_t)B_ * PB_ * 128 * 4);
    float*              part2  = (float*)             alloc((size_t)B_ * PB_ * 128 * 4);
    h8*                 wfrag  = (h8*)                alloc((size_t)2048 * 16);
    unsigned int*       xg     = (unsigned int*)bufB;   // alias

    // ---- one-time W fragment prep ----
    k_wprep<<<1, 128, 0, stream>>>(W1, W2, wfrag);

    // ---- stage 1 ----
    hipMemsetAsync(deg, 0, (size_t)NTOT * 4, stream);
    k_bucket<1><<<B_ * SLICES_, 256, 0, stream>>>(src, dst, nullptr, bcnt, blist, deg);
    k_prescale<1><<<2048, 256, 0, stream>>>(x, nullptr, deg, xb);
    k_scatconv<1><<<B_ * 16, 256, 0, stream>>>(xb, deg, bcnt, blist, wfrag, b1, p1, bufA, score);
    k_thresh<1><<<B_, 256, 0, stream>>>(score, thr);
    k_pool<1><<<B_ * PB_, 256, 0, stream>>>(score, bufA, thr, newid, xg, part1);

    // ---- stage 2 ----
    hipMemsetAsync(deg, 0, (size_t)N2TOT * 4, stream);
    k_bucket<2><<<B_ * SLICES_, 256, 0, stream>>>(src, dst, newid, bcnt, blist, deg);
    k_prescale<2><<<2048, 256, 0, stream>>>(nullptr, xg, deg, xb);
    k_scatconv<2><<<B_ * 13, 256, 0, stream>>>(xb, deg, bcnt, blist, wfrag, b2, p2, bufB, score);
    k_thresh<2><<<B_, 256, 0, stream>>>(score, thr);
    k_pool<2><<<B_ * PB_, 256, 0, stream>>>(score, bufB, thr, nullptr, nullptr, part2);

    // ---- head (combines both stages' partials) ----
    k_head<<<B_, 64, 0, stream>>>(part1, part2, l1w, l1b, l2w, l2b, (float*)d_out);
}

// Round 11
// 297.882 us; speedup vs baseline: 4.9099x; 4.9099x over previous
//
#include <hip/hip_runtime.h>
#include <hip/hip_bf16.h>
#include <cstdint>
#include <cstddef>

#define B_    64
#define N_    2048
#define E_    32768            // edges per graph
#define DIM_  64
#define K1_   1639
#define K2_   1312
#define NTOT  (B_ * N_)        // 131072
#define ETOT  (B_ * E_)        // 2097152
#define N2TOT (B_ * K1_)       // 104896
#define NCLS  6
#define PB_   8                // pool blocks per graph (index-partitioned)
#define CHUNKS_ 16             // dst-chunks per graph
#define SLICES_ 16             // edge slices per graph in k_bucket
#define BCAP  3072             // bucket capacity (= SLICES_*REG_)
#define REG_  192              // per-slice region (mean 128, sd ~11 -> +5.8 sigma)

typedef float f4 __attribute__((ext_vector_type(4)));
typedef _Float16 h2 __attribute__((ext_vector_type(2)));
typedef _Float16 h8 __attribute__((ext_vector_type(8)));

static __device__ __forceinline__ float fdot2(h2 a, h2 b, float c) {
    return __builtin_amdgcn_fdot2(a, b, c, false);
}
static __device__ __forceinline__ h2 pkrtz(float a, float b) {
    return __builtin_bit_cast(h2, __builtin_amdgcn_cvt_pkrtz(a, b));
}
static __device__ __forceinline__ unsigned long long mk_key(float s, int i) {
    unsigned u = __float_as_uint(s);
    u = (u & 0x80000000u) ? ~u : (u | 0x80000000u);
    return ((unsigned long long)u << 11) | (unsigned long long)(2047 - i);
}

// ---------------- one-time W fragment prep: f16 hi/lo MFMA B-fragments --------------------
// layout: wf[stage][ks][nt][hl][lane] as h8 (16B); 1024 h8 per stage (16KB)
__launch_bounds__(128)
__global__ void k_wprep(const float* W1, const float* W2, h8* wf) {
    int t = threadIdx.x;
    int stage = t >> 6, lane = t & 63;
    const float* W = stage ? W2 : W1;
    int q = lane >> 4, c = lane & 15;
#pragma unroll
    for (int ks = 0; ks < 2; ks++)
#pragma unroll
        for (int nt = 0; nt < 4; nt++) {
            h8 h, l;
#pragma unroll
            for (int j = 0; j < 8; j++) {
                float wv = W[(ks * 32 + q * 8 + j) * 64 + nt * 16 + c];
                _Float16 hh = (_Float16)wv;
                h[j] = hh;
                l[j] = (_Float16)(wv - (float)hh);
            }
            wf[(size_t)stage * 1024 + (((ks * 4 + nt) * 2 + 0) * 64) + lane] = h;
            wf[(size_t)stage * 1024 + (((ks * 4 + nt) * 2 + 1) * 64) + lane] = l;
        }
}

// ---------------- bucket edges by (graph, dst-chunk) into slice-owned regions --------------
template<int STAGE>
__launch_bounds__(256)
__global__ void k_bucket(const int* src, const int* dst, const int* remap,
                         int* bcnt, unsigned int* blist) {
    const int LSTR = (STAGE == 1) ? 128 : 103;
    __shared__ unsigned int lb[CHUNKS_][REG_];
    __shared__ int lc[CHUNKS_];
    __shared__ int rm[N_];                     // stage2 only
    int b = blockIdx.x;
    int g = b & 63, slice = b >> 6;
    int tid = threadIdx.x;
    if (tid < CHUNKS_) lc[tid] = 0;
    if (STAGE == 2)
        for (int i = tid; i < N_; i += 256) rm[i] = remap[g * N_ + i];
    __syncthreads();
    const int ESL = E_ / SLICES_;              // 2048
    const int* sp = src + (size_t)g * E_ + slice * ESL;
    const int* dp = dst + (size_t)g * E_ + slice * ESL;
    int gbase = g * ((STAGE == 1) ? N_ : K1_);
    for (int e = tid * 4; e < ESL; e += 1024) {
        int4 ss = *(const int4*)&sp[e];
        int4 dd = *(const int4*)&dp[e];
#pragma unroll
        for (int t = 0; t < 4; t++) {
            int s = (&ss.x)[t], d = (&dd.x)[t];
            if (STAGE == 2) {
                s = rm[s & (N_ - 1)]; d = rm[d & (N_ - 1)];
                if ((s | d) < 0) continue;     // edge touches a dropped node
                s -= gbase; d -= gbase;
            } else {
                s &= (N_ - 1); d &= (N_ - 1);
            }
            int ch = d / LSTR;
            int dl = d - ch * LSTR;
            int p = atomicAdd(&lc[ch], 1);
            if (p < REG_) lb[ch][p] = ((unsigned)dl << 12) | (unsigned)s;
        }
    }
    __syncthreads();
    for (int ch = 0; ch < CHUNKS_; ch++) {
        int n = min(lc[ch], REG_);
        unsigned int* out = blist + (size_t)(g * CHUNKS_ + ch) * BCAP + slice * REG_;
        for (int i = tid; i < n; i += 256) out[i] = lb[ch][i];
    }
    if (tid < CHUNKS_) bcnt[(g * SLICES_ + slice) * CHUNKS_ + tid] = min(lc[tid], REG_);
}

// ---------------- counting-sort -> in-place compact CSR (byte offsets) + ninfo + prescale ---
template<int STAGE>
__launch_bounds__(256)
__global__ void k_sort(const int* bcnt, unsigned int* blist,
                       const float* xf, const unsigned int* xg,
                       unsigned int* xb, int* ninfo) {
    const int NL   = (STAGE == 1) ? N_ : K1_;
    const int LSTR = (STAGE == 1) ? 128 : 103;
    __shared__ int cnt[128], st[128], cur[128], cnt_s[SLICES_], stot[2];
    __shared__ float rsqv[128];
    __shared__ unsigned short sorted[BCAP];
    int b = blockIdx.x;
    int g = b & 63, ch = b >> 6;
    int tid = threadIdx.x;
    if (tid < 128) { cnt[tid] = 0; cur[tid] = 0; }
    if (tid < SLICES_) cnt_s[tid] = bcnt[(g * SLICES_ + tid) * CHUNKS_ + ch];
    __syncthreads();
    size_t bb = (size_t)(g * CHUNKS_ + ch) * BCAP;
    const unsigned int* bl = blist + bb;
    const int TOT = SLICES_ * REG_;            // 3072
    for (int i = tid; i < TOT; i += 256) {
        int s = i / REG_, j = i - s * REG_;
        if (j < cnt_s[s]) atomicAdd(&cnt[bl[i] >> 12], 1);
    }
    __syncthreads();
    if (tid < 128) {
        int v = cnt[tid];
        int l64 = tid & 63;
#pragma unroll
        for (int o = 1; o < 64; o <<= 1) {
            int t = __shfl_up(v, o);
            if (l64 >= o) v += t;
        }
        st[tid] = v;
        if (l64 == 63) stot[tid >> 6] = v;
    }
    __syncthreads();
    if (tid >= 64 && tid < 128) st[tid] += stot[0];
    __syncthreads();
    for (int i = tid; i < TOT; i += 256) {
        int s = i / REG_, j = i - s * REG_;
        if (j < cnt_s[s]) {
            unsigned pk = bl[i];
            int dl = (int)(pk >> 12);
            int p = st[dl] - cnt[dl] + atomicAdd(&cur[dl], 1);
            sorted[p] = (unsigned short)(pk & 0xFFFu);
        }
    }
    __syncthreads();
    int n = st[127];
    // store source-row BYTE offset within graph (local_idx * 128)
    for (int i = tid; i < n; i += 256) blist[bb + i] = ((unsigned int)sorted[i]) << 7;
    int lo = ch * LSTR;
    int nloc = min(LSTR, NL - lo);
    int gbase = g * NL;
    if (tid < nloc) {
        int node = gbase + lo + tid;
        int c = cnt[tid];
        int start = (int)bb + st[tid] - c;
        ninfo[node] = (start << 8) | min(c, 255);
        rsqv[tid] = rsqrtf((float)(c + 1));
    }
    __syncthreads();
    for (int idx = tid; idx < nloc * 32; idx += 256) {
        int nl = idx >> 5, f2 = idx & 31;
        int node = gbase + lo + nl;
        float sc = rsqv[nl];
        float2 v;
        if (STAGE == 1) {
            v = ((const float2*)xf)[(size_t)node * 32 + f2];
        } else {
            h2 hv = __builtin_bit_cast(h2, xg[(size_t)node * 32 + f2]);
            v.x = (float)hv.x; v.y = (float)hv.y;
        }
        h2 o = {(_Float16)(v.x * sc), (_Float16)(v.y * sc)};
        xb[(size_t)node * 32 + f2] = __builtin_bit_cast(unsigned int, o);
    }
}

// ---------------- FUSED gather-aggregate + MFMA conv --------------------------------------
// Agg (dwordx2 gather): wave = 2 nodes (one per half); within a half, the two 16-lane
// sub-groups process edges i and i+1 simultaneously, each lane loading 8B = 4 features.
// Per 4 edges: 1 bpermute + 1 add + 1 dwordx2 load + 4 fdot2/lane -> 1.75 instr/edge vs
// r9's 2.5, and half the loop iterations (shorter per-wave serial chain). Epilogue: one
// shfl_xor(16) merge + self row + float4 LDS write (same swizzled chunk layout).
// r8's failure modes avoided: no main-loop divergence, no deep reduction, no reg cache.
// Occupancy (r9 win, kept): LDS 16KB, W fragments read from global, launch_bounds(256,8).
template<bool GATE>
__launch_bounds__(256, 8)
__global__ void k_aggconv(const unsigned int* xb, const int* ninfo, const unsigned int* csr,
                          const h8* wfrag, const float* bias, const float* pvec,
                          float* y, float* score) {
    __shared__ float4 ls4[1024];               // 64 rows x 16 float4 chunks (swizzled), 16KB
    int b = blockIdx.x;
    int wg;
    if (GATE) {                                 // 1639 blocks: bijective m204 (q=204,r=7)
        int xcd = b & 7, k = b >> 3;
        wg = (xcd < 7 ? xcd * 205 : 1435 + (xcd - 7) * 204) + k;
    } else {                                    // 2048 blocks: 8 graphs per XCD
        wg = (b & 7) * 256 + (b >> 3);
    }
    int tid = threadIdx.x;
    int wid = tid >> 6, lane = tid & 63;
    int half = lane >> 5, l32 = lane & 31, hbase = half << 5;
    int grp = l32 >> 4;                        // sub-group: edge i (0) or i+1 (1)
    int off8 = (l32 & 15) * 8;                 // byte slice: features 4k..4k+3
    int rowbase = wg * 64 + wid * 16;

    const char* xbb = (const char*)xb;
    const h2 one0  = {(_Float16)1.0f, (_Float16)0.0f};
    const h2 zero1 = {(_Float16)0.0f, (_Float16)1.0f};
    int g0 = 0, bnd = 0;
    if (GATE) { g0 = (wg * 64) / K1_; bnd = (g0 + 1) * K1_; }
    auto gbyte = [&](int node) -> int {        // byte base of the node's graph in xb
        if (GATE) { int gr = (node >= bnd) ? (g0 + 1) : g0; return gr * (K1_ * 128); }
        return (node & ~(N_ - 1)) << 7;
    };

    // ---- phase 1: aggregate the wave's 16 rows into LDS ----
    int niv = 0;
    if (lane < 16) niv = ninfo[rowbase + lane];
    int ni = __shfl(niv, half);                // pair 0 info
    int gbb = gbyte(rowbase + half);
    int sv = 0;
    { int c0 = ni & 255; if (l32 < c0) sv = (int)csr[(ni >> 8) + l32] + gbb; }
#pragma unroll 1
    for (int p = 0; p < 8; p++) {
        int cnt = ni & 255, base = ni >> 8;
        int ni_n = 0, sv_n = 0, gbb_n = 0;     // prefetch next pair's first csr chunk
        if (p < 7) {
            ni_n = __shfl(niv, 2 * (p + 1) + half);
            gbb_n = gbyte(rowbase + 2 * (p + 1) + half);
            int cn = ni_n & 255;
            if (l32 < cn) sv_n = (int)csr[(ni_n >> 8) + l32] + gbb_n;
        }
        int rloc = wid * 16 + 2 * p + half;    // LDS row 0..63
        int node = wg * 64 + rloc;
        uint2 su = *(const uint2*)(xbb + (unsigned)(node * 128 + off8));
        float a0[4] = {0.f, 0.f, 0.f, 0.f};    // chain 0: features 4k..4k+3
        float a1[4] = {0.f, 0.f, 0.f, 0.f};    // chain 1
        int svc = sv;
        for (int chunk = 0; chunk < cnt; chunk += 32) {
            int nch = min(32, cnt - chunk);
            if (chunk) svc = (l32 < nch) ? (int)csr[base + chunk + l32] + gbb : 0;
            int i = 0;
            for (; i + 8 <= nch; i += 8) {     // 4 instr-sets = 8 edges per half
                int e0 = __shfl(svc, hbase + i     + grp);
                int e1 = __shfl(svc, hbase + i + 2 + grp);
                int e2 = __shfl(svc, hbase + i + 4 + grp);
                int e3 = __shfl(svc, hbase + i + 6 + grp);
                uint2 u0 = *(const uint2*)(xbb + (unsigned)(e0 + off8));
                uint2 u1 = *(const uint2*)(xbb + (unsigned)(e1 + off8));
                uint2 u2 = *(const uint2*)(xbb + (unsigned)(e2 + off8));
                uint2 u3 = *(const uint2*)(xbb + (unsigned)(e3 + off8));
                {
                    h2 lo = __builtin_bit_cast(h2, u0.x), hi = __builtin_bit_cast(h2, u0.y);
                    a0[0] = fdot2(lo, one0, a0[0]); a0[1] = fdot2(lo, zero1, a0[1]);
                    a0[2] = fdot2(hi, one0, a0[2]); a0[3] = fdot2(hi, zero1, a0[3]);
                }
                {
                    h2 lo = __builtin_bit_cast(h2, u1.x), hi = __builtin_bit_cast(h2, u1.y);
                    a1[0] = fdot2(lo, one0, a1[0]); a1[1] = fdot2(lo, zero1, a1[1]);
                    a1[2] = fdot2(hi, one0, a1[2]); a1[3] = fdot2(hi, zero1, a1[3]);
                }
                {
                    h2 lo = __builtin_bit_cast(h2, u2.x), hi = __builtin_bit_cast(h2, u2.y);
                    a0[0] = fdot2(lo, one0, a0[0]); a0[1] = fdot2(lo, zero1, a0[1]);
                    a0[2] = fdot2(hi, one0, a0[2]); a0[3] = fdot2(hi, zero1, a0[3]);
                }
                {
                    h2 lo = __builtin_bit_cast(h2, u3.x), hi = __builtin_bit_cast(h2, u3.y);
                    a1[0] = fdot2(lo, one0, a1[0]); a1[1] = fdot2(lo, zero1, a1[1]);
                    a1[2] = fdot2(hi, one0, a1[2]); a1[3] = fdot2(hi, zero1, a1[3]);
                }
            }
            for (; i < nch; i += 2) {          // tail: 1-2 edges per half
                int my = i + grp;
                int e = __shfl(svc, hbase + (my < nch ? my : 0));
                if (my < nch) {
                    uint2 u = *(const uint2*)(xbb + (unsigned)(e + off8));
                    h2 lo = __builtin_bit_cast(h2, u.x), hi = __builtin_bit_cast(h2, u.y);
                    a0[0] = fdot2(lo, one0, a0[0]); a0[1] = fdot2(lo, zero1, a0[1]);
                    a0[2] = fdot2(hi, one0, a0[2]); a0[3] = fdot2(hi, zero1, a0[3]);
                }
            }
        }
        // merge chains + cross-group (edge-parity) merge
        float f[4];
#pragma unroll
        for (int w = 0; w < 4; w++) {
            f[w] = a0[w] + a1[w];
            f[w] += __shfl_xor(f[w], 16);
        }
        // self-loop term (duplicated across sub-groups; harmless)
        {
            h2 lo = __builtin_bit_cast(h2, su.x), hi = __builtin_bit_cast(h2, su.y);
            f[0] = fdot2(lo, one0, f[0]); f[1] = fdot2(lo, zero1, f[1]);
            f[2] = fdot2(hi, one0, f[2]); f[3] = fdot2(hi, zero1, f[3]);
        }
        float rd = rsqrtf((float)(cnt + 1));
        if (grp == 0) {                        // lanes 0-15 of each half write the row
            int k = l32 & 15;
            int cchunk = k ^ (rloc & 7);       // 16B-chunk XOR swizzle
            ls4[rloc * 16 + cchunk] =
                make_float4(f[0] * rd, f[1] * rd, f[2] * rd, f[3] * rd);
        }
        ni = ni_n; sv = sv_n; gbb = gbb_n;
    }
    __syncthreads();

    // ---- phase 2: conv = relu(agg @ W + b), score = tanh(conv.p/||p||) ----
    const h8* wsrc = wfrag + (GATE ? 1024 : 0);
    int q = lane >> 4, c = lane & 15;
    int rl16 = (wid * 16 + c) * 16;            // float4 row base in LDS
    int cx = c & 7;
    h8 ah[2], al[2];
#pragma unroll
    for (int ks = 0; ks < 2; ks++) {
        float4 v0 = ls4[rl16 + ((ks * 8 + q * 2 + 0) ^ cx)];
        float4 v1 = ls4[rl16 + ((ks * 8 + q * 2 + 1) ^ cx)];
        float vv[8] = {v0.x, v0.y, v0.z, v0.w, v1.x, v1.y, v1.z, v1.w};
        h8 h, l;
#pragma unroll
        for (int j = 0; j < 8; j += 2) {
            h2 hp = pkrtz(vv[j], vv[j + 1]);
            float r0 = vv[j]     - (float)hp.x;
            float r1 = vv[j + 1] - (float)hp.y;
            h2 lp = pkrtz(r0, r1);
            h[j] = hp.x; h[j + 1] = hp.y;
            l[j] = lp.x; l[j + 1] = lp.y;
        }
        ah[ks] = h; al[ks] = l;
    }
    float pp = 0.f;
#pragma unroll
    for (int i = 0; i < DIM_; i++) pp += pvec[i] * pvec[i];
    float rpn = rsqrtf(pp);
    float dot[4] = {0.f, 0.f, 0.f, 0.f};
#pragma unroll
    for (int nt = 0; nt < 4; nt++) {
        f4 acc = {0.f, 0.f, 0.f, 0.f};
#pragma unroll
        for (int ks = 0; ks < 2; ks++) {
            h8 wh = wsrc[(((ks * 4 + nt) * 2 + 0) * 64) + lane];
            h8 wl = wsrc[(((ks * 4 + nt) * 2 + 1) * 64) + lane];
            acc = __builtin_amdgcn_mfma_f32_16x16x32_f16(ah[ks], wh, acc, 0, 0, 0);
            acc = __builtin_amdgcn_mfma_f32_16x16x32_f16(ah[ks], wl, acc, 0, 0, 0);
            acc = __builtin_amdgcn_mfma_f32_16x16x32_f16(al[ks], wh, acc, 0, 0, 0);
        }
        float bcol = bias[nt * 16 + c];
        float pcol = pvec[nt * 16 + c];
        float st[4];
#pragma unroll
        for (int reg = 0; reg < 4; reg++) {
            float v = fmaxf(acc[reg] + bcol, 0.f);
            st[reg] = v;
            dot[reg] += v * pcol;
        }
#pragma unroll
        for (int reg = 0; reg < 4; reg++)
            y[(size_t)(wg * 64 + wid * 16 + q * 4 + reg) * DIM_ + nt * 16 + c] = st[reg];
    }
#pragma unroll
    for (int m = 1; m < 16; m <<= 1) {
#pragma unroll
        for (int reg = 0; reg < 4; reg++) dot[reg] += __shfl_xor(dot[reg], m);
    }
    if (c == 0) {
#pragma unroll
        for (int reg = 0; reg < 4; reg++)
            score[wg * 64 + wid * 16 + q * 4 + reg] = tanhf(dot[reg] * rpn);
    }
}

// ---------------- exact K-th-largest key per graph (6-pass radix) --------------
template<int STAGE>
__launch_bounds__(256)
__global__ void k_thresh(const float* score, unsigned long long* thresh) {
    const int Nin = (STAGE == 1) ? N_ : K1_;
    const int K   = (STAGE == 1) ? K1_ : K2_;
    __shared__ unsigned long long keys[N_];
    __shared__ int bins[256], wsum[4];
    __shared__ unsigned long long s_prefix;
    __shared__ int s_need;
    int g = blockIdx.x, tid = threadIdx.x;
    int l64 = tid & 63, wid = tid >> 6;
    const float* sg = score + (size_t)g * Nin;
    for (int i = tid; i < Nin; i += 256) keys[i] = mk_key(sg[i], i);
    if (tid == 0) { s_need = K; s_prefix = 0ull; }
    __syncthreads();
    for (int shift = 40; shift >= 0; shift -= 8) {
        bins[tid] = 0;
        __syncthreads();
        unsigned long long pref = s_prefix;
        int need = s_need;
        int hi = shift + 8;
        for (int i = tid; i < Nin; i += 256) {
            unsigned long long k = keys[i];
            if ((k >> hi) == pref) atomicAdd(&bins[(int)((k >> shift) & 255)], 1);
        }
        __syncthreads();
        int mine = bins[tid];
        int v = mine;
#pragma unroll
        for (int o = 1; o < 64; o <<= 1) {     // wave suffix scan
            int t = __shfl_down(v, o);
            if (l64 + o < 64) v += t;
        }
        if (l64 == 0) wsum[wid] = v;
        __syncthreads();
        for (int w = wid + 1; w < 4; w++) v += wsum[w];
        int nxt = v - mine;
        if (v >= need && nxt < need) {         // exactly one tid matches
            s_prefix = (pref << 8) | (unsigned long long)tid;
            s_need = need - nxt;
        }
        __syncthreads();
    }
    if (tid == 0) thresh[g] = s_prefix;
}

// ---------------- pool (+rank/newid/xg in stage1), PB_ blocks/graph, threshold handoff ------
template<int STAGE>
__launch_bounds__(256)
__global__ void k_pool(const float* score, const float* conv, const unsigned long long* thresh,
                       int* new_id, unsigned int* xg, float* part) {
    const int Nin = (STAGE == 1) ? N_ : K1_;
    const int RNG = (STAGE == 1) ? (N_ / PB_) : ((K1_ + PB_ - 1) / PB_);  // 256 / 205
    __shared__ int rnk[256];
    __shared__ unsigned char keepf[256];
    __shared__ int wsum[4], s_base[4];
    __shared__ float rmx[4][64], rsm[4][64];
    int b = blockIdx.x;
    int g = b & 63, pb = b >> 6;
    int tid = threadIdx.x;
    int l64 = tid & 63, wid = tid >> 6;
    const float* sg = score + (size_t)g * Nin;
    unsigned long long T = thresh[g];
    int R0 = pb * RNG;
    int R1 = min(R0 + RNG, Nin);
    if (STAGE == 1) {
        int cb = 0;
        for (int i = tid; i < R0; i += 256) cb += (mk_key(sg[i], i) >= T) ? 1 : 0;
#pragma unroll
        for (int o = 32; o; o >>= 1) cb += __shfl_down(cb, o);
        if (l64 == 0) s_base[wid] = cb;
        int i = R0 + tid;
        int keep = (i < R1 && mk_key(sg[i], i) >= T) ? 1 : 0;
        keepf[tid] = (unsigned char)keep;
        int v = keep;
#pragma unroll
        for (int o = 1; o < 64; o <<= 1) {
            int t = __shfl_up(v, o);
            if (l64 >= o) v += t;
        }
        if (l64 == 63) wsum[wid] = v;
        __syncthreads();
        int base = s_base[0] + s_base[1] + s_base[2] + s_base[3];
        int wbase = 0;
        for (int w = 0; w < wid; w++) wbase += wsum[w];
        int r = base + wbase + v - keep;
        rnk[tid] = r;
        if (i < Nin) new_id[g * N_ + i] = keep ? (g * K1_ + r) : -1;
    } else {
        int i = R0 + tid;
        keepf[tid] = (unsigned char)((i < R1 && mk_key(sg[i], i) >= T) ? 1 : 0);
    }
    __syncthreads();
    float mx = -3.402823466e38f, sm = 0.f;
    for (int i = R0 + wid; i < R1; i += 4) {
        if (!keepf[i - R0]) continue;
        float val = sg[i];
        float v = conv[(size_t)(g * Nin + i) * DIM_ + l64] * val;
        mx = fmaxf(mx, v);
        sm += v;
        if (STAGE == 1) {
            float vo = __shfl_xor(v, 1);
            if (!(l64 & 1)) {
                h2 pk2 = {(_Float16)v, (_Float16)vo};
                xg[(size_t)(g * K1_ + rnk[i - R0]) * 32 + (l64 >> 1)] =
                    __builtin_bit_cast(unsigned int, pk2);
            }
        }
    }
    rmx[wid][l64] = mx; rsm[wid][l64] = sm;
    __syncthreads();
    if (wid == 0) {
        mx = fmaxf(fmaxf(rmx[0][l64], rmx[1][l64]), fmaxf(rmx[2][l64], rmx[3][l64]));
        sm = rsm[0][l64] + rsm[1][l64] + rsm[2][l64] + rsm[3][l64];
        part[((size_t)(g * PB_ + pb) * 2 + 0) * 64 + l64] = mx;
        part[((size_t)(g * PB_ + pb) * 2 + 1) * 64 + l64] = sm;
    }
}

// ---------------- MLP head (combines both stages' partials) ----------------
__launch_bounds__(64)
__global__ void k_head(const float* part1, const float* part2,
                       const float* l1w, const float* l1b,
                       const float* l2w, const float* l2b, float* out) {
    __shared__ float h[128];
    __shared__ float h1[64];
    int g = blockIdx.x, t = threadIdx.x;
    float mx1 = -3.402823466e38f, sm1 = 0.f, mx2 = -3.402823466e38f, sm2 = 0.f;
#pragma unroll
    for (int c = 0; c < PB_; c++) {
        mx1 = fmaxf(mx1, part1[((size_t)(g * PB_ + c) * 2 + 0) * 64 + t]);
        sm1 += part1[((size_t)(g * PB_ + c) * 2 + 1) * 64 + t];
        mx2 = fmaxf(mx2, part2[((size_t)(g * PB_ + c) * 2 + 0) * 64 + t]);
        sm2 += part2[((size_t)(g * PB_ + c) * 2 + 1) * 64 + t];
    }
    h[t]      = mx1 + mx2;
    h[t + 64] = sm1 / (float)K1_ + sm2 / (float)K2_;
    __syncthreads();
    float acc = l1b[t];
#pragma unroll 8
    for (int i = 0; i < 128; i++) acc += h[i] * l1w[i * 64 + t];
    h1[t] = fmaxf(acc, 0.0f);
    __syncthreads();
    if (t < NCLS) {
        float o = l2b[t];
#pragma unroll
        for (int i = 0; i < 64; i++) o += h1[i] * l2w[i * NCLS + t];
        out[g * NCLS + t] = o;
    }
}

extern "C" void kernel_launch(void* const* d_in, const int* in_sizes, int n_in,
                              void* d_out, int out_size, void* d_ws, size_t ws_size,
                              hipStream_t stream) {
    const float* x   = (const float*)d_in[0];
    const int*   ei  = (const int*)d_in[1];
    const int*   src = ei;
    const int*   dst = ei + ETOT;
    const float* W1  = (const float*)d_in[3];
    const float* b1  = (const float*)d_in[4];
    const float* p1  = (const float*)d_in[5];
    const float* W2  = (const float*)d_in[6];
    const float* b2  = (const float*)d_in[7];
    const float* p2  = (const float*)d_in[8];
    const float* l1w = (const float*)d_in[9];
    const float* l1b = (const float*)d_in[10];
    const float* l2w = (const float*)d_in[11];
    const float* l2b = (const float*)d_in[12];
    (void)in_sizes; (void)n_in; (void)out_size; (void)ws_size;

    // workspace layout (~92 MB); xg aliases bufB (dead until aggconv2 writes it)
    char* ws = (char*)d_ws;
    size_t off = 0;
    auto alloc = [&](size_t bytes) -> void* {
        void* p = ws + off;
        off = (off + bytes + 255) & ~(size_t)255;
        return p;
    };
    float*              bufA   = (float*)             alloc((size_t)NTOT  * DIM_ * 4);
    float*              bufB   = (float*)             alloc((size_t)N2TOT * DIM_ * 4);
    unsigned int*       blist  = (unsigned int*)      alloc((size_t)B_ * CHUNKS_ * BCAP * 4);
    unsigned int*       xb     = (unsigned int*)      alloc((size_t)NTOT * 32 * 4);
    int*                bcnt   = (int*)               alloc((size_t)B_ * SLICES_ * CHUNKS_ * 4);
    int*                ninfo  = (int*)               alloc((size_t)NTOT * 4);
    float*              score  = (float*)             alloc((size_t)NTOT * 4);
    int*                newid  = (int*)               alloc((size_t)NTOT * 4);
    unsigned long long* thr    = (unsigned long long*)alloc((size_t)B_ * 8);
    float*              part1  = (float*)             alloc((size_t)B_ * PB_ * 128 * 4);
    float*              part2  = (float*)             alloc((size_t)B_ * PB_ * 128 * 4);
    h8*                 wfrag  = (h8*)                alloc((size_t)2048 * 16);
    unsigned int*       xg     = (unsigned int*)bufB;   // alias

    // ---- one-time W fragment prep ----
    k_wprep<<<1, 128, 0, stream>>>(W1, W2, wfrag);

    // ---- stage 1 ----
    k_bucket<1><<<B_ * SLICES_, 256, 0, stream>>>(src, dst, nullptr, bcnt, blist);
    k_sort<1><<<B_ * CHUNKS_, 256, 0, stream>>>(bcnt, blist, x, nullptr, xb, ninfo);
    k_aggconv<false><<<NTOT / 64, 256, 0, stream>>>(xb, ninfo, blist, wfrag, b1, p1, bufA, score);
    k_thresh<1><<<B_, 256, 0, stream>>>(score, thr);
    k_pool<1><<<B_ * PB_, 256, 0, stream>>>(score, bufA, thr, newid, xg, part1);

    // ---- stage 2 ----
    k_bucket<2><<<B_ * SLICES_, 256, 0, stream>>>(src, dst, newid, bcnt, blist);
    k_sort<2><<<B_ * CHUNKS_, 256, 0, stream>>>(bcnt, blist, nullptr, xg, xb, ninfo);
    k_aggconv<true><<<N2TOT / 64, 256, 0, stream>>>(xb, ninfo, blist, wfrag, b2, p2, bufB, score);
    k_thresh<2><<<B_, 256, 0, stream>>>(score, thr);
    k_pool<2><<<B_ * PB_, 256, 0, stream>>>(score, bufB, thr, nullptr, nullptr, part2);

    // ---- head (combines both stages' partials) ----
    k_head<<<B_, 64, 0, stream>>>(part1, part2, l1w, l1b, l2w, l2b, (float*)d_out);
}

// Round 12
// 296.838 us; speedup vs baseline: 4.9272x; 1.0035x over previous
//
#include <hip/hip_runtime.h>
#include <hip/hip_bf16.h>
#include <cstdint>
#include <cstddef>

#define B_    64
#define N_    2048
#define E_    32768            // edges per graph
#define DIM_  64
#define K1_   1639
#define K2_   1312
#define NTOT  (B_ * N_)        // 131072
#define ETOT  (B_ * E_)        // 2097152
#define N2TOT (B_ * K1_)       // 104896
#define NCLS  6
#define PB_   8                // pool blocks per graph (index-partitioned)
#define CHUNKS_ 16             // dst-chunks per graph
#define SLICES_ 16             // edge slices per graph in k_bucket
#define BCAP  3072             // bucket capacity (= SLICES_*REG_)
#define REG_  192              // per-slice region (mean 128, sd ~11 -> +5.8 sigma)

typedef float f4 __attribute__((ext_vector_type(4)));
typedef _Float16 h2 __attribute__((ext_vector_type(2)));
typedef _Float16 h8 __attribute__((ext_vector_type(8)));

static __device__ __forceinline__ float fdot2(h2 a, h2 b, float c) {
    return __builtin_amdgcn_fdot2(a, b, c, false);
}
static __device__ __forceinline__ h2 pkrtz(float a, float b) {
    return __builtin_bit_cast(h2, __builtin_amdgcn_cvt_pkrtz(a, b));
}
static __device__ __forceinline__ unsigned long long mk_key(float s, int i) {
    unsigned u = __float_as_uint(s);
    u = (u & 0x80000000u) ? ~u : (u | 0x80000000u);
    return ((unsigned long long)u << 11) | (unsigned long long)(2047 - i);
}

// ---------------- one-time W fragment prep: f16 hi/lo MFMA B-fragments --------------------
// layout: wf[stage][ks][nt][hl][lane] as h8 (16B); 1024 h8 per stage (16KB)
__launch_bounds__(128)
__global__ void k_wprep(const float* W1, const float* W2, h8* wf) {
    int t = threadIdx.x;
    int stage = t >> 6, lane = t & 63;
    const float* W = stage ? W2 : W1;
    int q = lane >> 4, c = lane & 15;
#pragma unroll
    for (int ks = 0; ks < 2; ks++)
#pragma unroll
        for (int nt = 0; nt < 4; nt++) {
            h8 h, l;
#pragma unroll
            for (int j = 0; j < 8; j++) {
                float wv = W[(ks * 32 + q * 8 + j) * 64 + nt * 16 + c];
                _Float16 hh = (_Float16)wv;
                h[j] = hh;
                l[j] = (_Float16)(wv - (float)hh);
            }
            wf[(size_t)stage * 1024 + (((ks * 4 + nt) * 2 + 0) * 64) + lane] = h;
            wf[(size_t)stage * 1024 + (((ks * 4 + nt) * 2 + 1) * 64) + lane] = l;
        }
}

// ---------------- bucket edges by (graph, dst-chunk) into slice-owned regions --------------
template<int STAGE>
__launch_bounds__(256)
__global__ void k_bucket(const int* src, const int* dst, const int* remap,
                         int* bcnt, unsigned int* blist) {
    const int LSTR = (STAGE == 1) ? 128 : 103;
    __shared__ unsigned int lb[CHUNKS_][REG_];
    __shared__ int lc[CHUNKS_];
    __shared__ int rm[N_];                     // stage2 only
    int b = blockIdx.x;
    int g = b & 63, slice = b >> 6;
    int tid = threadIdx.x;
    if (tid < CHUNKS_) lc[tid] = 0;
    if (STAGE == 2)
        for (int i = tid; i < N_; i += 256) rm[i] = remap[g * N_ + i];
    __syncthreads();
    const int ESL = E_ / SLICES_;              // 2048
    const int* sp = src + (size_t)g * E_ + slice * ESL;
    const int* dp = dst + (size_t)g * E_ + slice * ESL;
    int gbase = g * ((STAGE == 1) ? N_ : K1_);
    for (int e = tid * 4; e < ESL; e += 1024) {
        int4 ss = *(const int4*)&sp[e];
        int4 dd = *(const int4*)&dp[e];
#pragma unroll
        for (int t = 0; t < 4; t++) {
            int s = (&ss.x)[t], d = (&dd.x)[t];
            if (STAGE == 2) {
                s = rm[s & (N_ - 1)]; d = rm[d & (N_ - 1)];
                if ((s | d) < 0) continue;     // edge touches a dropped node
                s -= gbase; d -= gbase;
            } else {
                s &= (N_ - 1); d &= (N_ - 1);
            }
            int ch = d / LSTR;
            int dl = d - ch * LSTR;
            int p = atomicAdd(&lc[ch], 1);
            if (p < REG_) lb[ch][p] = ((unsigned)dl << 12) | (unsigned)s;
        }
    }
    __syncthreads();
    for (int ch = 0; ch < CHUNKS_; ch++) {
        int n = min(lc[ch], REG_);
        unsigned int* out = blist + (size_t)(g * CHUNKS_ + ch) * BCAP + slice * REG_;
        for (int i = tid; i < n; i += 256) out[i] = lb[ch][i];
    }
    if (tid < CHUNKS_) bcnt[(g * SLICES_ + slice) * CHUNKS_ + tid] = min(lc[tid], REG_);
}

// ---------------- counting-sort -> in-place compact CSR (byte offsets) + ninfo + prescale ---
template<int STAGE>
__launch_bounds__(256)
__global__ void k_sort(const int* bcnt, unsigned int* blist,
                       const float* xf, const unsigned int* xg,
                       unsigned int* xb, int* ninfo) {
    const int NL   = (STAGE == 1) ? N_ : K1_;
    const int LSTR = (STAGE == 1) ? 128 : 103;
    __shared__ int cnt[128], st[128], cur[128], cnt_s[SLICES_], stot[2];
    __shared__ float rsqv[128];
    __shared__ unsigned short sorted[BCAP];
    int b = blockIdx.x;
    int g = b & 63, ch = b >> 6;
    int tid = threadIdx.x;
    if (tid < 128) { cnt[tid] = 0; cur[tid] = 0; }
    if (tid < SLICES_) cnt_s[tid] = bcnt[(g * SLICES_ + tid) * CHUNKS_ + ch];
    __syncthreads();
    size_t bb = (size_t)(g * CHUNKS_ + ch) * BCAP;
    const unsigned int* bl = blist + bb;
    const int TOT = SLICES_ * REG_;            // 3072
    for (int i = tid; i < TOT; i += 256) {
        int s = i / REG_, j = i - s * REG_;
        if (j < cnt_s[s]) atomicAdd(&cnt[bl[i] >> 12], 1);
    }
    __syncthreads();
    if (tid < 128) {
        int v = cnt[tid];
        int l64 = tid & 63;
#pragma unroll
        for (int o = 1; o < 64; o <<= 1) {
            int t = __shfl_up(v, o);
            if (l64 >= o) v += t;
        }
        st[tid] = v;
        if (l64 == 63) stot[tid >> 6] = v;
    }
    __syncthreads();
    if (tid >= 64 && tid < 128) st[tid] += stot[0];
    __syncthreads();
    for (int i = tid; i < TOT; i += 256) {
        int s = i / REG_, j = i - s * REG_;
        if (j < cnt_s[s]) {
            unsigned pk = bl[i];
            int dl = (int)(pk >> 12);
            int p = st[dl] - cnt[dl] + atomicAdd(&cur[dl], 1);
            sorted[p] = (unsigned short)(pk & 0xFFFu);
        }
    }
    __syncthreads();
    int n = st[127];
    // store source-row BYTE offset within graph (local_idx * 128)
    for (int i = tid; i < n; i += 256) blist[bb + i] = ((unsigned int)sorted[i]) << 7;
    int lo = ch * LSTR;
    int nloc = min(LSTR, NL - lo);
    int gbase = g * NL;
    if (tid < nloc) {
        int node = gbase + lo + tid;
        int c = cnt[tid];
        int start = (int)bb + st[tid] - c;
        ninfo[node] = (start << 8) | min(c, 255);
        rsqv[tid] = rsqrtf((float)(c + 1));
    }
    __syncthreads();
    for (int idx = tid; idx < nloc * 32; idx += 256) {
        int nl = idx >> 5, f2 = idx & 31;
        int node = gbase + lo + nl;
        float sc = rsqv[nl];
        float2 v;
        if (STAGE == 1) {
            v = ((const float2*)xf)[(size_t)node * 32 + f2];
        } else {
            h2 hv = __builtin_bit_cast(h2, xg[(size_t)node * 32 + f2]);
            v.x = (float)hv.x; v.y = (float)hv.y;
        }
        h2 o = {(_Float16)(v.x * sc), (_Float16)(v.y * sc)};
        xb[(size_t)node * 32 + f2] = __builtin_bit_cast(unsigned int, o);
    }
}

// ---------------- FUSED gather-aggregate + MFMA conv --------------------------------------
// Agg: wave wid aggregates rows [wid*16,+16) two at a time (half-wave chains), f16 rows
// accumulated via v_dot2_f32_f16, byte-offset CSR addressing (round-5 structure = best).
// OCCUPANCY (r9 win): LDS 16KB (no W cache -> 8 blocks/CU); W fragments read from global
// (L2-hit, once per block); launch_bounds(256,8). r11 evidence: the kernel runs at the
// per-CU L1-miss concurrency cap (~10.3 B/cy/CU = 32 lines x 64B / 200cy L2 latency) --
// instruction count, load depth, addressing form all immaterial at this point.
template<bool GATE>
__launch_bounds__(256, 8)
__global__ void k_aggconv(const unsigned int* xb, const int* ninfo, const unsigned int* csr,
                          const h8* wfrag, const float* bias, const float* pvec,
                          float* y, float* score) {
    __shared__ float4 ls4[1024];               // 64 rows x 64 floats (swizzled), 16KB
    float* ls = (float*)ls4;
    int b = blockIdx.x;
    int wg;
    if (GATE) {                                 // 1639 blocks: bijective m204 (q=204,r=7)
        int xcd = b & 7, k = b >> 3;
        wg = (xcd < 7 ? xcd * 205 : 1435 + (xcd - 7) * 204) + k;
    } else {                                    // 2048 blocks: 8 graphs per XCD
        wg = (b & 7) * 256 + (b >> 3);
    }
    int tid = threadIdx.x;
    int wid = tid >> 6, lane = tid & 63;
    int half = lane >> 5, l32 = lane & 31, hbase = half << 5;
    int l32_4 = l32 << 2;
    int rowbase = wg * 64 + wid * 16;

    const char* xbb = (const char*)xb;
    const h2 one0  = {(_Float16)1.0f, (_Float16)0.0f};
    const h2 zero1 = {(_Float16)0.0f, (_Float16)1.0f};
    int g0 = 0, bnd = 0;
    if (GATE) { g0 = (wg * 64) / K1_; bnd = (g0 + 1) * K1_; }
    auto gbyte = [&](int node) -> int {        // byte base of the node's graph in xb
        if (GATE) { int gr = (node >= bnd) ? (g0 + 1) : g0; return gr * (K1_ * 128); }
        return (node & ~(N_ - 1)) << 7;
    };

    // ---- phase 1: aggregate the wave's 16 rows into LDS ----
    int niv = 0;
    if (lane < 16) niv = ninfo[rowbase + lane];
    int ni = __shfl(niv, half);                // pair 0 info
    int gbb = gbyte(rowbase + half);
    int sv = 0;
    { int c0 = ni & 255; if (l32 < c0) sv = (int)csr[(ni >> 8) + l32] + gbb; }
#pragma unroll 1
    for (int p = 0; p < 8; p++) {
        int cnt = ni & 255, base = ni >> 8;
        int ni_n = 0, sv_n = 0, gbb_n = 0;     // prefetch next pair's first csr chunk
        if (p < 7) {
            ni_n = __shfl(niv, 2 * (p + 1) + half);
            gbb_n = gbyte(rowbase + 2 * (p + 1) + half);
            int cn = ni_n & 255;
            if (l32 < cn) sv_n = (int)csr[(ni_n >> 8) + l32] + gbb_n;
        }
        int rloc = wid * 16 + 2 * p + half;    // LDS row 0..63
        int node = wg * 64 + rloc;
        unsigned selfu = *(const unsigned*)(xbb + (unsigned)(node * 128 + l32_4));
        float acx[4] = {0.f, 0.f, 0.f, 0.f};
        float acy[4] = {0.f, 0.f, 0.f, 0.f};
        int svc = sv;
        for (int chunk = 0; chunk < cnt; chunk += 32) {
            int nch = min(32, cnt - chunk);
            if (chunk) svc = (l32 < nch) ? (int)csr[base + chunk + l32] + gbb : 0;
            int i = 0;
            for (; i + 16 <= nch; i += 16) {
                int e[16]; unsigned u[16];
#pragma unroll
                for (int k = 0; k < 16; k++) e[k] = __shfl(svc, hbase + i + k);
#pragma unroll
                for (int k = 0; k < 16; k++)
                    u[k] = *(const unsigned*)(xbb + (unsigned)(e[k] + l32_4));
#pragma unroll
                for (int k = 0; k < 16; k++) {
                    h2 h = __builtin_bit_cast(h2, u[k]);
                    acx[k & 3] = fdot2(h, one0,  acx[k & 3]);
                    acy[k & 3] = fdot2(h, zero1, acy[k & 3]);
                }
            }
            for (; i + 8 <= nch; i += 8) {
                int e[8]; unsigned u[8];
#pragma unroll
                for (int k = 0; k < 8; k++) e[k] = __shfl(svc, hbase + i + k);
#pragma unroll
                for (int k = 0; k < 8; k++)
                    u[k] = *(const unsigned*)(xbb + (unsigned)(e[k] + l32_4));
#pragma unroll
                for (int k = 0; k < 8; k++) {
                    h2 h = __builtin_bit_cast(h2, u[k]);
                    acx[k & 3] = fdot2(h, one0,  acx[k & 3]);
                    acy[k & 3] = fdot2(h, zero1, acy[k & 3]);
                }
            }
            for (; i + 4 <= nch; i += 4) {
                int e[4]; unsigned u[4];
#pragma unroll
                for (int k = 0; k < 4; k++) e[k] = __shfl(svc, hbase + i + k);
#pragma unroll
                for (int k = 0; k < 4; k++)
                    u[k] = *(const unsigned*)(xbb + (unsigned)(e[k] + l32_4));
#pragma unroll
                for (int k = 0; k < 4; k++) {
                    h2 h = __builtin_bit_cast(h2, u[k]);
                    acx[k] = fdot2(h, one0,  acx[k]);
                    acy[k] = fdot2(h, zero1, acy[k]);
                }
            }
            for (; i < nch; i++) {
                int e = __shfl(svc, hbase + i);
                h2 h = __builtin_bit_cast(h2, *(const unsigned*)(xbb + (unsigned)(e + l32_4)));
                acx[0] = fdot2(h, one0,  acx[0]);
                acy[0] = fdot2(h, zero1, acy[0]);
            }
        }
        // self-loop term
        {
            h2 sh = __builtin_bit_cast(h2, selfu);
            acx[0] = fdot2(sh, one0,  acx[0]);
            acy[0] = fdot2(sh, zero1, acy[0]);
        }
        float rd = rsqrtf((float)(cnt + 1));
        float2 o;
        o.x = ((acx[0] + acx[1]) + (acx[2] + acx[3])) * rd;
        o.y = ((acy[0] + acy[1]) + (acy[2] + acy[3])) * rd;
        // swizzled store: dwords d=2*l32..+1 -> 16B chunk (l32>>1)^(rloc&7)
        int pi = rloc * 32 + ((((l32 >> 1) ^ (rloc & 7)) << 1) | (l32 & 1));
        ((float2*)ls)[pi] = o;
        ni = ni_n; sv = sv_n; gbb = gbb_n;
    }
    __syncthreads();

    // ---- phase 2: conv = relu(agg @ W + b), score = tanh(conv.p/||p||) ----
    const h8* wsrc = wfrag + (GATE ? 1024 : 0);
    int q = lane >> 4, c = lane & 15;
    int rl16 = (wid * 16 + c) * 16;            // float4 row base in LDS
    int cx = c & 7;
    h8 ah[2], al[2];
#pragma unroll
    for (int ks = 0; ks < 2; ks++) {
        float4 v0 = ls4[rl16 + ((ks * 8 + q * 2 + 0) ^ cx)];
        float4 v1 = ls4[rl16 + ((ks * 8 + q * 2 + 1) ^ cx)];
        float vv[8] = {v0.x, v0.y, v0.z, v0.w, v1.x, v1.y, v1.z, v1.w};
        h8 h, l;
#pragma unroll
        for (int j = 0; j < 8; j += 2) {
            h2 hp = pkrtz(vv[j], vv[j + 1]);
            float r0 = vv[j]     - (float)hp.x;
            float r1 = vv[j + 1] - (float)hp.y;
            h2 lp = pkrtz(r0, r1);
            h[j] = hp.x; h[j + 1] = hp.y;
            l[j] = lp.x; l[j + 1] = lp.y;
        }
        ah[ks] = h; al[ks] = l;
    }
    float pp = 0.f;
#pragma unroll
    for (int i = 0; i < DIM_; i++) pp += pvec[i] * pvec[i];
    float rpn = rsqrtf(pp);
    float dot[4] = {0.f, 0.f, 0.f, 0.f};
#pragma unroll
    for (int nt = 0; nt < 4; nt++) {
        f4 acc = {0.f, 0.f, 0.f, 0.f};
#pragma unroll
        for (int ks = 0; ks < 2; ks++) {
            h8 wh = wsrc[(((ks * 4 + nt) * 2 + 0) * 64) + lane];
            h8 wl = wsrc[(((ks * 4 + nt) * 2 + 1) * 64) + lane];
            acc = __builtin_amdgcn_mfma_f32_16x16x32_f16(ah[ks], wh, acc, 0, 0, 0);
            acc = __builtin_amdgcn_mfma_f32_16x16x32_f16(ah[ks], wl, acc, 0, 0, 0);
            acc = __builtin_amdgcn_mfma_f32_16x16x32_f16(al[ks], wh, acc, 0, 0, 0);
        }
        float bcol = bias[nt * 16 + c];
        float pcol = pvec[nt * 16 + c];
        float st[4];
#pragma unroll
        for (int reg = 0; reg < 4; reg++) {
            float v = fmaxf(acc[reg] + bcol, 0.f);
            st[reg] = v;
            dot[reg] += v * pcol;
        }
#pragma unroll
        for (int reg = 0; reg < 4; reg++)
            y[(size_t)(wg * 64 + wid * 16 + q * 4 + reg) * DIM_ + nt * 16 + c] = st[reg];
    }
#pragma unroll
    for (int m = 1; m < 16; m <<= 1) {
#pragma unroll
        for (int reg = 0; reg < 4; reg++) dot[reg] += __shfl_xor(dot[reg], m);
    }
    if (c == 0) {
#pragma unroll
        for (int reg = 0; reg < 4; reg++)
            score[wg * 64 + wid * 16 + q * 4 + reg] = tanhf(dot[reg] * rpn);
    }
}

// ---------------- exact K-th-largest key per graph (6-pass radix) --------------
template<int STAGE>
__launch_bounds__(256)
__global__ void k_thresh(const float* score, unsigned long long* thresh) {
    const int Nin = (STAGE == 1) ? N_ : K1_;
    const int K   = (STAGE == 1) ? K1_ : K2_;
    __shared__ unsigned long long keys[N_];
    __shared__ int bins[256], wsum[4];
    __shared__ unsigned long long s_prefix;
    __shared__ int s_need;
    int g = blockIdx.x, tid = threadIdx.x;
    int l64 = tid & 63, wid = tid >> 6;
    const float* sg = score + (size_t)g * Nin;
    for (int i = tid; i < Nin; i += 256) keys[i] = mk_key(sg[i], i);
    if (tid == 0) { s_need = K; s_prefix = 0ull; }
    __syncthreads();
    for (int shift = 40; shift >= 0; shift -= 8) {
        bins[tid] = 0;
        __syncthreads();
        unsigned long long pref = s_prefix;
        int need = s_need;
        int hi = shift + 8;
        for (int i = tid; i < Nin; i += 256) {
            unsigned long long k = keys[i];
            if ((k >> hi) == pref) atomicAdd(&bins[(int)((k >> shift) & 255)], 1);
        }
        __syncthreads();
        int mine = bins[tid];
        int v = mine;
#pragma unroll
        for (int o = 1; o < 64; o <<= 1) {     // wave suffix scan
            int t = __shfl_down(v, o);
            if (l64 + o < 64) v += t;
        }
        if (l64 == 0) wsum[wid] = v;
        __syncthreads();
        for (int w = wid + 1; w < 4; w++) v += wsum[w];
        int nxt = v - mine;
        if (v >= need && nxt < need) {         // exactly one tid matches
            s_prefix = (pref << 8) | (unsigned long long)tid;
            s_need = need - nxt;
        }
        __syncthreads();
    }
    if (tid == 0) thresh[g] = s_prefix;
}

// ---------------- pool (+rank/newid/xg in stage1), PB_ blocks/graph, threshold handoff ------
template<int STAGE>
__launch_bounds__(256)
__global__ void k_pool(const float* score, const float* conv, const unsigned long long* thresh,
                       int* new_id, unsigned int* xg, float* part) {
    const int Nin = (STAGE == 1) ? N_ : K1_;
    const int RNG = (STAGE == 1) ? (N_ / PB_) : ((K1_ + PB_ - 1) / PB_);  // 256 / 205
    __shared__ int rnk[256];
    __shared__ unsigned char keepf[256];
    __shared__ int wsum[4], s_base[4];
    __shared__ float rmx[4][64], rsm[4][64];
    int b = blockIdx.x;
    int g = b & 63, pb = b >> 6;
    int tid = threadIdx.x;
    int l64 = tid & 63, wid = tid >> 6;
    const float* sg = score + (size_t)g * Nin;
    unsigned long long T = thresh[g];
    int R0 = pb * RNG;
    int R1 = min(R0 + RNG, Nin);
    if (STAGE == 1) {
        int cb = 0;
        for (int i = tid; i < R0; i += 256) cb += (mk_key(sg[i], i) >= T) ? 1 : 0;
#pragma unroll
        for (int o = 32; o; o >>= 1) cb += __shfl_down(cb, o);
        if (l64 == 0) s_base[wid] = cb;
        int i = R0 + tid;
        int keep = (i < R1 && mk_key(sg[i], i) >= T) ? 1 : 0;
        keepf[tid] = (unsigned char)keep;
        int v = keep;
#pragma unroll
        for (int o = 1; o < 64; o <<= 1) {
            int t = __shfl_up(v, o);
            if (l64 >= o) v += t;
        }
        if (l64 == 63) wsum[wid] = v;
        __syncthreads();
        int base = s_base[0] + s_base[1] + s_base[2] + s_base[3];
        int wbase = 0;
        for (int w = 0; w < wid; w++) wbase += wsum[w];
        int r = base + wbase + v - keep;
        rnk[tid] = r;
        if (i < Nin) new_id[g * N_ + i] = keep ? (g * K1_ + r) : -1;
    } else {
        int i = R0 + tid;
        keepf[tid] = (unsigned char)((i < R1 && mk_key(sg[i], i) >= T) ? 1 : 0);
    }
    __syncthreads();
    float mx = -3.402823466e38f, sm = 0.f;
    for (int i = R0 + wid; i < R1; i += 4) {
        if (!keepf[i - R0]) continue;
        float val = sg[i];
        float v = conv[(size_t)(g * Nin + i) * DIM_ + l64] * val;
        mx = fmaxf(mx, v);
        sm += v;
        if (STAGE == 1) {
            float vo = __shfl_xor(v, 1);
            if (!(l64 & 1)) {
                h2 pk2 = {(_Float16)v, (_Float16)vo};
                xg[(size_t)(g * K1_ + rnk[i - R0]) * 32 + (l64 >> 1)] =
                    __builtin_bit_cast(unsigned int, pk2);
            }
        }
    }
    rmx[wid][l64] = mx; rsm[wid][l64] = sm;
    __syncthreads();
    if (wid == 0) {
        mx = fmaxf(fmaxf(rmx[0][l64], rmx[1][l64]), fmaxf(rmx[2][l64], rmx[3][l64]));
        sm = rsm[0][l64] + rsm[1][l64] + rsm[2][l64] + rsm[3][l64];
        part[((size_t)(g * PB_ + pb) * 2 + 0) * 64 + l64] = mx;
        part[((size_t)(g * PB_ + pb) * 2 + 1) * 64 + l64] = sm;
    }
}

// ---------------- MLP head (combines both stages' partials) ----------------
__launch_bounds__(64)
__global__ void k_head(const float* part1, const float* part2,
                       const float* l1w, const float* l1b,
                       const float* l2w, const float* l2b, float* out) {
    __shared__ float h[128];
    __shared__ float h1[64];
    int g = blockIdx.x, t = threadIdx.x;
    float mx1 = -3.402823466e38f, sm1 = 0.f, mx2 = -3.402823466e38f, sm2 = 0.f;
#pragma unroll
    for (int c = 0; c < PB_; c++) {
        mx1 = fmaxf(mx1, part1[((size_t)(g * PB_ + c) * 2 + 0) * 64 + t]);
        sm1 += part1[((size_t)(g * PB_ + c) * 2 + 1) * 64 + t];
        mx2 = fmaxf(mx2, part2[((size_t)(g * PB_ + c) * 2 + 0) * 64 + t]);
        sm2 += part2[((size_t)(g * PB_ + c) * 2 + 1) * 64 + t];
    }
    h[t]      = mx1 + mx2;
    h[t + 64] = sm1 / (float)K1_ + sm2 / (float)K2_;
    __syncthreads();
    float acc = l1b[t];
#pragma unroll 8
    for (int i = 0; i < 128; i++) acc += h[i] * l1w[i * 64 + t];
    h1[t] = fmaxf(acc, 0.0f);
    __syncthreads();
    if (t < NCLS) {
        float o = l2b[t];
#pragma unroll
        for (int i = 0; i < 64; i++) o += h1[i] * l2w[i * NCLS + t];
        out[g * NCLS + t] = o;
    }
}

extern "C" void kernel_launch(void* const* d_in, const int* in_sizes, int n_in,
                              void* d_out, int out_size, void* d_ws, size_t ws_size,
                              hipStream_t stream) {
    const float* x   = (const float*)d_in[0];
    const int*   ei  = (const int*)d_in[1];
    const int*   src = ei;
    const int*   dst = ei + ETOT;
    const float* W1  = (const float*)d_in[3];
    const float* b1  = (const float*)d_in[4];
    const float* p1  = (const float*)d_in[5];
    const float* W2  = (const float*)d_in[6];
    const float* b2  = (const float*)d_in[7];
    const float* p2  = (const float*)d_in[8];
    const float* l1w = (const float*)d_in[9];
    const float* l1b = (const float*)d_in[10];
    const float* l2w = (const float*)d_in[11];
    const float* l2b = (const float*)d_in[12];
    (void)in_sizes; (void)n_in; (void)out_size; (void)ws_size;

    // workspace layout (~92 MB); xg aliases bufB (dead until aggconv2 writes it)
    char* ws = (char*)d_ws;
    size_t off = 0;
    auto alloc = [&](size_t bytes) -> void* {
        void* p = ws + off;
        off = (off + bytes + 255) & ~(size_t)255;
        return p;
    };
    float*              bufA   = (float*)             alloc((size_t)NTOT  * DIM_ * 4);
    float*              bufB   = (float*)             alloc((size_t)N2TOT * DIM_ * 4);
    unsigned int*       blist  = (unsigned int*)      alloc((size_t)B_ * CHUNKS_ * BCAP * 4);
    unsigned int*       xb     = (unsigned int*)      alloc((size_t)NTOT * 32 * 4);
    int*                bcnt   = (int*)               alloc((size_t)B_ * SLICES_ * CHUNKS_ * 4);
    int*                ninfo  = (int*)               alloc((size_t)NTOT * 4);
    float*              score  = (float*)             alloc((size_t)NTOT * 4);
    int*                newid  = (int*)               alloc((size_t)NTOT * 4);
    unsigned long long* thr    = (unsigned long long*)alloc((size_t)B_ * 8);
    float*              part1  = (float*)             alloc((size_t)B_ * PB_ * 128 * 4);
    float*              part2  = (float*)             alloc((size_t)B_ * PB_ * 128 * 4);
    h8*                 wfrag  = (h8*)                alloc((size_t)2048 * 16);
    unsigned int*       xg     = (unsigned int*)bufB;   // alias

    // ---- one-time W fragment prep ----
    k_wprep<<<1, 128, 0, stream>>>(W1, W2, wfrag);

    // ---- stage 1 ----
    k_bucket<1><<<B_ * SLICES_, 256, 0, stream>>>(src, dst, nullptr, bcnt, blist);
    k_sort<1><<<B_ * CHUNKS_, 256, 0, stream>>>(bcnt, blist, x, nullptr, xb, ninfo);
    k_aggconv<false><<<NTOT / 64, 256, 0, stream>>>(xb, ninfo, blist, wfrag, b1, p1, bufA, score);
    k_thresh<1><<<B_, 256, 0, stream>>>(score, thr);
    k_pool<1><<<B_ * PB_, 256, 0, stream>>>(score, bufA, thr, newid, xg, part1);

    // ---- stage 2 ----
    k_bucket<2><<<B_ * SLICES_, 256, 0, stream>>>(src, dst, newid, bcnt, blist);
    k_sort<2><<<B_ * CHUNKS_, 256, 0, stream>>>(bcnt, blist, nullptr, xg, xb, ninfo);
    k_aggconv<true><<<N2TOT / 64, 256, 0, stream>>>(xb, ninfo, blist, wfrag, b2, p2, bufB, score);
    k_thresh<2><<<B_, 256, 0, stream>>>(score, thr);
    k_pool<2><<<B_ * PB_, 256, 0, stream>>>(score, bufB, thr, nullptr, nullptr, part2);

    // ---- head (combines both stages' partials) ----
    k_head<<<B_, 64, 0, stream>>>(part1, part2, l1w, l1b, l2w, l2b, (float*)d_out);
}